// Round 13
// baseline (1118.146 us; speedup 1.0000x reference)
//
#include <hip/hip_runtime.h>

#define HCH 512      // channels
#define LSEQ 4096    // sequence length
#define HSTR (LSEQ + 4)  // padded row stride: 1 front pad + 3 back pad rows
#define NB 32        // batch
#define KW 3         // conv kernel width
#define KDIM 1536    // HCH*KW, GEMM K
#define INVS 0.9999950000374997f  // 1/sqrt(1+1e-5)
#define NT 24        // GEMM K-steps of 64

typedef __attribute__((ext_vector_type(8))) short bf16x8;
typedef __attribute__((ext_vector_type(4))) float f32x4;

__device__ inline unsigned short f2bf(float f) {
  unsigned int u = __float_as_uint(f);
  u += 0x7fffu + ((u >> 16) & 1u);
  return (unsigned short)(u >> 16);
}

__device__ inline void gl_lds16(const void* g, void* l) {
  __builtin_amdgcn_global_load_lds(
      (const __attribute__((address_space(1))) void*)g,
      (__attribute__((address_space(3))) void*)l, 16, 0, 0);
}

// ---- fused prep: zero zeropage+partial+h-pads, chunk prefix sum, w transpose
__global__ void prep_all(const float* __restrict__ w1, const float* __restrict__ w2,
                         const float* __restrict__ pw, unsigned short* __restrict__ wt,
                         const int* __restrict__ seq_lens, int* __restrict__ cum,
                         float* __restrict__ pz, int nz,
                         unsigned short* __restrict__ hbuf, int nbp) {
  int idx = blockIdx.x * 256 + threadIdx.x;
  if (idx < nz) pz[idx] = 0.f;
  if (idx == 0) {
    int acc = 0;
    for (int b = 0; b < NB; b++) {
      cum[b] = acc;
      acc += (seq_lens[b] - KW) / KW + 1;
    }
  }
  // zero pad rows of both h ping-pong buffers: rows {0, 4097, 4098, 4099}/batch
  int npads = 2 * nbp * 4 * HCH;
  if (idx < npads) {
    int per = nbp * 4 * HCH;
    int buf = idx / per, r = idx % per;
    int b = r / (4 * HCH), rr = r % (4 * HCH);
    int j = rr / HCH, c = rr % HCH;
    int row = (j == 0) ? 0 : (LSEQ + j);
    hbuf[((size_t)buf * nbp + b) * HSTR * HCH + (size_t)row * HCH + c] = 0;
  }
  if (idx < 3 * HCH * KDIM) {
    int which = idx / (HCH * KDIM);
    int r = idx % (HCH * KDIM);
    int c = r / KDIM;
    int rem = r % KDIM;
    int k = rem / HCH, ci = rem % HCH;
    const float* src = (which == 0) ? w1 : ((which == 1) ? w2 : pw);
    wt[idx] = f2bf(src[c * KDIM + ci * KW + k]);
  }
}

// ---- layer 0: 1->512 conv + relu + scale/shift, fp32 in, bf16 (b,row,C) out
__global__ void layer0(const float* __restrict__ x, const float* __restrict__ w0,
                       const float* __restrict__ b0, const float* __restrict__ g0,
                       const float* __restrict__ be0, unsigned short* __restrict__ h0,
                       const int* __restrict__ seq_q) {
  int tid = threadIdx.x;
  int wave = tid >> 6, lane = tid & 63;
  int pos0 = (blockIdx.x * 4 + wave) * 8;      // flattened (b_local*4096 + l)
  int l0 = pos0 & (LSEQ - 1);
  int bq = pos0 >> 12;
  if (l0 >= seq_q[bq] + 2) return;             // h0 needed only for l <= slen+1
  int c0 = lane * 8;

  float w[24], bb[8], gg[8], ee[8];
  for (int v = 0; v < 6; v++)
    *reinterpret_cast<float4*>(w + v * 4) = *reinterpret_cast<const float4*>(w0 + c0 * 3 + v * 4);
  for (int v = 0; v < 2; v++) {
    *reinterpret_cast<float4*>(bb + v * 4) = *reinterpret_cast<const float4*>(b0 + c0 + v * 4);
    *reinterpret_cast<float4*>(gg + v * 4) = *reinterpret_cast<const float4*>(g0 + c0 + v * 4);
    *reinterpret_cast<float4*>(ee + v * 4) = *reinterpret_cast<const float4*>(be0 + c0 + v * 4);
  }
  for (int c = 0; c < 8; c++) gg[c] *= INVS;

  const float* xb = x + (size_t)(pos0 - l0);   // batch base
  unsigned short* hrow = h0 + ((size_t)bq * HSTR + 1 + l0) * HCH + c0;
  for (int pp = 0; pp < 8; pp++) {
    int l = l0 + pp;
    float xm1 = (l > 0) ? xb[l - 1] : 0.f;
    float xc = xb[l];
    float xp1 = (l < LSEQ - 1) ? xb[l + 1] : 0.f;
    unsigned int o[4];
    for (int pq = 0; pq < 4; pq++) {
      unsigned int lo = 0, hi = 0;
      for (int s = 0; s < 2; s++) {
        int c = pq * 2 + s;
        float y = w[c * 3] * xm1 + w[c * 3 + 1] * xc + w[c * 3 + 2] * xp1 + bb[c];
        y = fmaxf(y, 0.f);
        unsigned int u = f2bf(gg[c] * y + ee[c]);
        if (s == 0) lo = u; else hi = u;
      }
      o[pq] = lo | (hi << 16);
    }
    uint4 v4; v4.x = o[0]; v4.y = o[1]; v4.z = o[2]; v4.w = o[3];
    *reinterpret_cast<uint4*>(hrow + (size_t)pp * HCH) = v4;
  }
}

#define BARRIER { asm volatile("" ::: "memory");                            \
                  __builtin_amdgcn_s_barrier();                             \
                  asm volatile("" ::: "memory"); }
#define WAITV(n) asm volatile("s_waitcnt vmcnt(" #n ")" ::: "memory");

// K-step t: k = t%3, ci0 = (t/3)*64  (k-inner => L2-hot k-slice reuse).
#define OFFK(T) (((T) % 3) * HCH + ((T) / 3) * 64)

#define MFMA_Q(MB, Nh)                                                      \
  __builtin_amdgcn_s_setprio(1);                                            \
  _Pragma("unroll") for (int i_ = 0; i_ < 4; ++i_)                          \
  _Pragma("unroll") for (int j_ = 0; j_ < 2; ++j_)                          \
  _Pragma("unroll") for (int s_ = 0; s_ < 2; ++s_)                          \
    acc[(MB) + i_][(Nh)*2 + j_] = __builtin_amdgcn_mfma_f32_16x16x32_bf16(  \
        af[i_][s_], bfv[Nh][j_][s_], acc[(MB) + i_][(Nh)*2 + j_], 0, 0, 0); \
  __builtin_amdgcn_s_setprio(0);

// ===== conv with A direct from L2 (no A-LDS at all) =======================
// A (the weight panel, 768 KB/cm-tile) is L2-resident — every block re-reads
// it.  The MFMA A-fragment is loaded straight global->VGPR:
//   af[i][s] = wT[(cm+Mh*128+wm+i*16+mr)*KDIM + OFFK(t) + s*32 + quad*8]
// (base per (Mh,i); OFFK*2 + s*64 <= 3008 B folds into the load immediate).
// This removes 2/3 of the LDS reads and 1/2 of the LDS writes; A traffic
// moves to the separate L2 path (128 KB/CU/step, ~16 TB/s agg << 34.5).
// A-loads need no barriers: compiler's exact waitcnt covers the af deps.
// B keeps the r3 3-deep LDS pipeline (96 KiB, 3 x 32 KB by t%3).
// Ledger: at step-t barrier, outstanding = B(t+1) (staged t-1).  Step t
// issues A0(8), A1(8), Bstage(t+2)(4) in that order; end-of-step WAITV(4)
// retires B(t+1)+A (A already forced by MFMA waits), leaves B(t+2) ->
// every wave's B(t+1) landed before the t+1 barrier (race-free).
#define LOAD_AG(Mh, T)                                                      \
  _Pragma("unroll") for (int i_ = 0; i_ < 4; ++i_)                          \
  _Pragma("unroll") for (int s_ = 0; s_ < 2; ++s_)                          \
    af[i_][s_] = *reinterpret_cast<const bf16x8*>(                          \
        aP[Mh][i_] + OFFK(T) + s_ * 32);

#define STAGE_B2(Nh, BB, TN)                                                \
  { char* d_ = ldsc + (BB) * 32768 + (Nh) * 16384 + w * 1024;               \
    gl_lds16(bSrc[Nh][0] + OFFK(TN), d_);                                   \
    gl_lds16(bSrc[Nh][1] + OFFK(TN), d_ + 8192); }

#define LOAD_BF2(Nh, BB)                                                    \
  _Pragma("unroll") for (int j_ = 0; j_ < 2; ++j_)                          \
  _Pragma("unroll") for (int s_ = 0; s_ < 2; ++s_)                          \
    bfv[Nh][j_][s_] = *reinterpret_cast<const bf16x8*>(                     \
        ldsb + (BB) * 16384 + (Nh) * 8192 + (wn + j_ * 16 + mr) * 64 +      \
        (((s_ * 4 + quad) ^ (mr & 7)) << 3));

#define STEPL(T)                                                            \
  {                                                                         \
    BARRIER;                                                                \
    bf16x8 af[4][2], bfv[2][2][2];                                          \
    LOAD_AG(0, T);                                                          \
    LOAD_BF2(0, (T) % 3); LOAD_BF2(1, (T) % 3);                             \
    MFMA_Q(0, 0); MFMA_Q(0, 1);                                             \
    LOAD_AG(1, T);                                                          \
    if ((T) + 2 < NT) { STAGE_B2(0, ((T)+2)%3, (T)+2);                      \
                        STAGE_B2(1, ((T)+2)%3, (T)+2); }                    \
    MFMA_Q(4, 1); MFMA_Q(4, 0);                                             \
    if ((T) + 2 < NT) { WAITV(4); } else { WAITV(0); }                      \
  }

__global__ __launch_bounds__(512, 2) void conv_gemmA(
    const unsigned short* __restrict__ hin,   // (nb,HSTR,C) bf16, padded
    const unsigned short* __restrict__ wT,    // (512, 1536) bf16 A-layout
    const float* __restrict__ bconv, const float* __restrict__ g,
    const float* __restrict__ be,
    unsigned short* __restrict__ hout,        // (nb,HSTR,C) bf16, padded
    const int* __restrict__ seq_q, int margin) {
  __shared__ unsigned short ldsb[49152];      // 96 KiB: B 3 x 32 KB tbuf

  int f = blockIdx.x;
  int cpx = gridDim.x >> 3;                   // gridDim.x % 8 == 0 by launch
  int s = (f & 7) * cpx + (f >> 3);
  int cm = (s & 1) << 8;                      // out-channel tile: 0 or 256
  int y = s >> 1;
  int b = y >> 4;                             // batch-local
  int l0 = (y & 15) << 8;                     // 256-position tile
  int limit = seq_q[b] + margin;              // outputs needed for n < limit
  if (l0 >= limit) return;                    // block-uniform, pre-barrier

  const size_t hb = (size_t)b * HSTR * HCH + HCH;  // +1 row front pad
  int tid = threadIdx.x;
  int w = tid >> 6, lane = tid & 63;
  int quad = lane >> 4, mr = lane & 15;
  int wm = (w >> 2) << 6;                     // 0/64 within A half
  int wn = (w & 3) << 5;                      // 0/32/64/96 within B half
  int srow = tid >> 3;                        // staging row 0..63 within group
  int sslot8 = (((tid & 7) ^ (srow & 7)) << 3);  // swizzled src offset (shorts)

  // A fragment base pointers: per (Mh, i) row group, lane-resolved
  const unsigned short* aP[2][4];
#pragma unroll
  for (int Mh = 0; Mh < 2; ++Mh)
#pragma unroll
    for (int i = 0; i < 4; ++i)
      aP[Mh][i] = wT + (size_t)(cm + Mh * 128 + wm + i * 16 + mr) * KDIM + quad * 8;

  const unsigned short* bSrc[2][2];
#pragma unroll
  for (int Nh = 0; Nh < 2; ++Nh)
#pragma unroll
    for (int g2 = 0; g2 < 2; ++g2)
      bSrc[Nh][g2] = hin + hb +
          (size_t)(l0 - 1 + Nh * 128 + g2 * 64 + srow) * HCH + sslot8;

  f32x4 acc[8][4] = {};
  char* ldsc = (char*)ldsb;

  // prologue: B(0) staged + landed-everywhere before first barrier; B(1) in flight
  STAGE_B2(0, 0, 0); STAGE_B2(1, 0, 0);
  WAITV(0);
  STAGE_B2(0, 1, 1); STAGE_B2(1, 1, 1);

  STEPL(0)  STEPL(1)  STEPL(2)  STEPL(3)  STEPL(4)  STEPL(5)
  STEPL(6)  STEPL(7)  STEPL(8)  STEPL(9)  STEPL(10) STEPL(11)
  STEPL(12) STEPL(13) STEPL(14) STEPL(15) STEPL(16) STEPL(17)
  STEPL(18) STEPL(19) STEPL(20) STEPL(21) STEPL(22) STEPL(23)

  // epilogue: relu(acc + b) * g*inv + be -> bf16; C/D: col=lane&15, row=quad*4+r
#pragma unroll
  for (int ai = 0; ai < 8; ++ai) {
    int Mh = ai >> 2, i = ai & 3;
    int c = cm + Mh * 128 + wm + i * 16 + quad * 4;
    f32x4 bc = *reinterpret_cast<const f32x4*>(bconv + c);
    f32x4 gg = *reinterpret_cast<const f32x4*>(g + c);
    f32x4 bb = *reinterpret_cast<const f32x4*>(be + c);
#pragma unroll
    for (int aj = 0; aj < 4; ++aj) {
      int Nh = aj >> 1, j = aj & 1;
      int n = l0 + Nh * 128 + wn + j * 16 + (lane & 15);
      if (n >= limit) continue;
      unsigned long long pack = 0;
#pragma unroll
      for (int r = 0; r < 4; ++r) {
        float yv = acc[ai][aj][r] + bc[r];
        yv = fmaxf(yv, 0.f);
        unsigned long long u = f2bf(gg[r] * INVS * yv + bb[r]);
        pack |= u << (16 * r);
      }
      *reinterpret_cast<unsigned long long*>(hout + hb + (size_t)n * HCH + c) = pack;
    }
  }
}

// ===== r8 machinery (chunk_gemm8, unchanged/verified) =====================
#define STAGE_A(Mh, AB, TN)                                                 \
  { char* d_ = ldsc + (AB) * 32768 + (Mh) * 16384 + w * 1024;               \
    gl_lds16(aSrc[Mh][0] + OFFK(TN), d_);                                   \
    gl_lds16(aSrc[Mh][1] + OFFK(TN), d_ + 8192); }

#define STAGE_B(Nh, BB, TN)                                                 \
  { char* d_ = ldsc + 65536 + (BB) * 32768 + (Nh) * 16384 + w * 1024;       \
    gl_lds16(bSrc[Nh][0] + OFFK(TN), d_);                                   \
    gl_lds16(bSrc[Nh][1] + OFFK(TN), d_ + 8192); }

#define LOAD_AF(Mh, AB)                                                     \
  _Pragma("unroll") for (int i_ = 0; i_ < 4; ++i_)                          \
  _Pragma("unroll") for (int s_ = 0; s_ < 2; ++s_)                          \
    af[i_][s_] = *reinterpret_cast<const bf16x8*>(                          \
        ldsb + (AB) * 16384 + (Mh) * 8192 + (wm + i_ * 16 + mr) * 64 +      \
        (((s_ * 4 + quad) ^ (mr & 7)) << 3));

#define LOAD_BF(Nh, BB)                                                     \
  _Pragma("unroll") for (int j_ = 0; j_ < 2; ++j_)                          \
  _Pragma("unroll") for (int s_ = 0; s_ < 2; ++s_)                          \
    bfv[Nh][j_][s_] = *reinterpret_cast<const bf16x8*>(                     \
        ldsb + 32768 + (BB) * 16384 + (Nh) * 8192 + (wn + j_ * 16 + mr) * 64 + \
        (((s_ * 4 + quad) ^ (mr & 7)) << 3));

#define STEP(T)                                                             \
  {                                                                         \
    if ((T) == NT - 1) { WAITV(0); } else { WAITV(4); }                     \
    BARRIER;                                                                \
    if ((T) + 1 < NT) { STAGE_A(0, ((T)+1)&1, (T)+1);                       \
                        STAGE_A(1, ((T)+1)&1, (T)+1); }                     \
    if ((T) + 2 < NT) { STAGE_B(0, ((T)+2)%3, (T)+2);                       \
                        STAGE_B(1, ((T)+2)%3, (T)+2); }                     \
    bf16x8 af[4][2], bfv[2][2][2];                                          \
    LOAD_AF(0, (T)&1);                                                      \
    LOAD_BF(0, (T)%3); LOAD_BF(1, (T)%3);                                   \
    MFMA_Q(0, 0); MFMA_Q(0, 1);                                             \
    LOAD_AF(1, (T)&1);                                                      \
    MFMA_Q(4, 1); MFMA_Q(4, 0);                                             \
  }

// ---- chunk einsum on the r3 pipeline + fused head ------------------------
__global__ __launch_bounds__(512, 2) void chunk_gemm8(
    const unsigned short* __restrict__ h2,    // (nb,HSTR,C) bf16, padded
    const unsigned short* __restrict__ wT,    // (512,1536) bf16 A-layout
    const float* __restrict__ pb, const float* __restrict__ fw,
    const int* __restrict__ seq_q,
    const int* __restrict__ cum_q,
    float* __restrict__ partial,
    const unsigned short* __restrict__ zp) {
  __shared__ unsigned short ldsb[81920];      // 160 KiB

  int f = blockIdx.x;
  int cpx = gridDim.x >> 3;                   // gridDim.x % 8 == 0 (192)
  int s = (f & 7) * cpx + (f >> 3);
  int cm = (s & 1) << 8;                      // channel tile 0/256
  int y = s >> 1;
  int b = y / 6;                              // batch-local
  int s_base = (y % 6) << 8;                  // 256-slot tile
  int slen = seq_q[b];
  if (3 * s_base + KW > slen) return;         // whole tile dead

  const size_t hb = (size_t)b * HSTR * HCH + HCH;
  int tid = threadIdx.x;
  int w = tid >> 6, lane = tid & 63;
  int quad = lane >> 4, mr = lane & 15;
  int wm = (w >> 2) << 6;
  int wn = (w & 3) << 5;
  int srow = tid >> 3;
  int sslot8 = (((tid & 7) ^ (srow & 7)) << 3);

  const unsigned short* aSrc[2][2];
#pragma unroll
  for (int Mh = 0; Mh < 2; ++Mh)
#pragma unroll
    for (int g2 = 0; g2 < 2; ++g2)
      aSrc[Mh][g2] = wT + (size_t)(cm + Mh * 128 + g2 * 64 + srow) * KDIM + sslot8;
  const unsigned short* bSrc[2][2];
#pragma unroll
  for (int Nh = 0; Nh < 2; ++Nh)
#pragma unroll
    for (int g2 = 0; g2 < 2; ++g2) {
      int slot = s_base + Nh * 128 + g2 * 64 + srow;
      bSrc[Nh][g2] = (slot <= 1365)
          ? h2 + hb + (size_t)(3 * slot) * HCH + sslot8
          : zp + sslot8;
    }

  f32x4 acc[8][4] = {};
  char* ldsc = (char*)ldsb;

  STAGE_A(0, 0, 0); STAGE_A(1, 0, 0);
  STAGE_B(0, 0, 0); STAGE_B(1, 0, 0);
  STAGE_B(0, 1, 1); STAGE_B(1, 1, 1);

  STEP(0)  STEP(1)  STEP(2)  STEP(3)  STEP(4)  STEP(5)
  STEP(6)  STEP(7)  STEP(8)  STEP(9)  STEP(10) STEP(11)
  STEP(12) STEP(13) STEP(14) STEP(15) STEP(16) STEP(17)
  STEP(18) STEP(19) STEP(20) STEP(21) STEP(22) STEP(23)

  // fused head: per slot, sum relu(acc+pb)*fw over this wave's 128 channels,
  // quad-reduce (quads hold disjoint channel groups), one atomic per slot.
  int nn = lane & 15;
#pragma unroll
  for (int aj = 0; aj < 4; ++aj) {
    int Nh = aj >> 1, jj = aj & 1;
    int sc = s_base + Nh * 128 + wn + jj * 16 + nn;
    float sacc = 0.f;
#pragma unroll
    for (int ai = 0; ai < 8; ++ai) {
      int Mh = ai >> 2, i = ai & 3;
      int c = cm + Mh * 128 + wm + i * 16 + quad * 4;
      f32x4 pbv = *reinterpret_cast<const f32x4*>(pb + c);
      f32x4 fwv = *reinterpret_cast<const f32x4*>(fw + c);
#pragma unroll
      for (int r = 0; r < 4; ++r) {
        float z = acc[ai][aj][r] + pbv[r];
        z = fmaxf(z, 0.f);
        sacc += z * fwv[r];
      }
    }
    sacc += __shfl_xor(sacc, 16, 64);
    sacc += __shfl_xor(sacc, 32, 64);
    if (quad == 0 && 3 * sc + KW <= slen)
      atomicAdd(partial + cum_q[b] + sc, sacc);
  }
}

// ---- final: sigmoid(partial + fb) ----------------------------------------
__global__ void finalize(const float* __restrict__ partial, const float* __restrict__ fb,
                         float* __restrict__ out, int n) {
  int i = blockIdx.x * 256 + threadIdx.x;
  if (i < n) {
    float t = partial[i] + fb[0];
    out[i] = 1.f / (1.f + expf(-t));
  }
}

extern "C" void kernel_launch(void* const* d_in, const int* in_sizes, int n_in,
                              void* d_out, int out_size, void* d_ws, size_t ws_size,
                              hipStream_t stream) {
  (void)in_sizes; (void)n_in;
  const float* x   = (const float*)d_in[0];
  const float* w0  = (const float*)d_in[1];
  const float* b0  = (const float*)d_in[2];
  const float* g0  = (const float*)d_in[3];
  const float* be0 = (const float*)d_in[4];
  const float* w1  = (const float*)d_in[5];
  const float* b1  = (const float*)d_in[6];
  const float* g1  = (const float*)d_in[7];
  const float* be1 = (const float*)d_in[8];
  const float* w2  = (const float*)d_in[9];
  const float* b2  = (const float*)d_in[10];
  const float* g2  = (const float*)d_in[11];
  const float* be2 = (const float*)d_in[12];
  const float* pw  = (const float*)d_in[13];
  const float* pb  = (const float*)d_in[14];
  const float* fw  = (const float*)d_in[15];
  const float* fb  = (const float*)d_in[16];
  const int* seq_lens = (const int*)d_in[17];

  char* ws = (char*)d_ws;
  unsigned short* zeropage = (unsigned short*)ws;          // 4096 B, zeroed
  float* partial = (float*)(ws + 4096);                    // out_size floats, zeroed
  size_t off = 4096 + (size_t)out_size * 4;
  off = (off + 255) & ~(size_t)255;
  int* cum = (int*)(ws + off);                             // NB ints
  off += NB * 4;
  off = (off + 255) & ~(size_t)255;
  unsigned short* wt = (unsigned short*)(ws + off);        // 3 x 512 x 1536 bf16
  off += (size_t)3 * HCH * KDIM * 2;
  off = (off + 255) & ~(size_t)255;
  size_t fixed = off;

  const size_t per_batch = (size_t)HSTR * HCH * 2;         // padded, ~4.2 MiB
  int nb_pass = NB;
  while (nb_pass > 1 && fixed + 2 * per_batch * (size_t)nb_pass > ws_size)
    nb_pass >>= 1;
  unsigned short* h0 = (unsigned short*)(ws + fixed);
  unsigned short* h1 = h0 + (size_t)nb_pass * HSTR * HCH;

  int nzero = 1024 + out_size;
  prep_all<<<(3 * HCH * KDIM) / 256, 256, 0, stream>>>(w1, w2, pw, wt, seq_lens, cum,
                                                       (float*)ws, nzero, h0, nb_pass);

  int npass = NB / nb_pass;
  for (int q = 0; q < npass; q++) {
    const float* xq = x + (size_t)q * nb_pass * LSEQ;
    const int* sq = seq_lens + q * nb_pass;
    int nwg = nb_pass * 32;                  // 2 cm-tiles x 16 l-tiles per batch
    layer0<<<nb_pass * (LSEQ / 32), 256, 0, stream>>>(xq, w0, b0, g0, be0, h0, sq);
    conv_gemmA<<<nwg, 512, 0, stream>>>(h0, wt, b1, g1, be1, h1, sq, 1);
    conv_gemmA<<<nwg, 512, 0, stream>>>(h1, wt + (size_t)HCH * KDIM, b2, g2, be2, h0,
                                        sq, 0);
    int nwg2 = nb_pass * 12;                 // 2 cm-tiles x 6 slot-tiles per batch
    chunk_gemm8<<<nwg2, 512, 0, stream>>>(h0, wt + (size_t)2 * HCH * KDIM, pb, fw,
                                          sq, cum + q * nb_pass, partial, zeropage);
  }
  finalize<<<(out_size + 255) / 256, 256, 0, stream>>>(partial, fb, (float*)d_out, out_size);
}

// Round 14
// 555.772 us; speedup vs baseline: 2.0119x; 2.0119x over previous
//
#include <hip/hip_runtime.h>

#define HCH 512      // channels
#define LSEQ 4096    // sequence length
#define HSTR (LSEQ + 4)  // padded row stride: 1 front pad + 3 back pad rows
#define NB 32        // batch
#define KW 3         // conv kernel width
#define KDIM 1536    // HCH*KW, GEMM K
#define INVS 0.9999950000374997f  // 1/sqrt(1+1e-5)
#define NT 24        // GEMM K-steps of 64

typedef __attribute__((ext_vector_type(8))) short bf16x8;
typedef __attribute__((ext_vector_type(4))) float f32x4;

__device__ inline unsigned short f2bf(float f) {
  unsigned int u = __float_as_uint(f);
  u += 0x7fffu + ((u >> 16) & 1u);
  return (unsigned short)(u >> 16);
}

__device__ inline void gl_lds16(const void* g, void* l) {
  __builtin_amdgcn_global_load_lds(
      (const __attribute__((address_space(1))) void*)g,
      (__attribute__((address_space(3))) void*)l, 16, 0, 0);
}

// ---- fused prep: zero zeropage+partial+h-pads, chunk prefix sum, w transpose
__global__ void prep_all(const float* __restrict__ w1, const float* __restrict__ w2,
                         const float* __restrict__ pw, unsigned short* __restrict__ wt,
                         const int* __restrict__ seq_lens, int* __restrict__ cum,
                         float* __restrict__ pz, int nz,
                         unsigned short* __restrict__ hbuf, int nbp) {
  int idx = blockIdx.x * 256 + threadIdx.x;
  if (idx < nz) pz[idx] = 0.f;
  if (idx == 0) {
    int acc = 0;
    for (int b = 0; b < NB; b++) {
      cum[b] = acc;
      acc += (seq_lens[b] - KW) / KW + 1;
    }
  }
  // zero pad rows of both h ping-pong buffers: rows {0, 4097, 4098, 4099}/batch
  int npads = 2 * nbp * 4 * HCH;
  if (idx < npads) {
    int per = nbp * 4 * HCH;
    int buf = idx / per, r = idx % per;
    int b = r / (4 * HCH), rr = r % (4 * HCH);
    int j = rr / HCH, c = rr % HCH;
    int row = (j == 0) ? 0 : (LSEQ + j);
    hbuf[((size_t)buf * nbp + b) * HSTR * HCH + (size_t)row * HCH + c] = 0;
  }
  if (idx < 3 * HCH * KDIM) {
    int which = idx / (HCH * KDIM);
    int r = idx % (HCH * KDIM);
    int c = r / KDIM;
    int rem = r % KDIM;
    int k = rem / HCH, ci = rem % HCH;
    const float* src = (which == 0) ? w1 : ((which == 1) ? w2 : pw);
    wt[idx] = f2bf(src[c * KDIM + ci * KW + k]);
  }
}

// ---- layer 0: 1->512 conv + relu + scale/shift, fp32 in, bf16 (b,row,C) out
__global__ void layer0(const float* __restrict__ x, const float* __restrict__ w0,
                       const float* __restrict__ b0, const float* __restrict__ g0,
                       const float* __restrict__ be0, unsigned short* __restrict__ h0,
                       const int* __restrict__ seq_q) {
  int tid = threadIdx.x;
  int wave = tid >> 6, lane = tid & 63;
  int pos0 = (blockIdx.x * 4 + wave) * 8;      // flattened (b_local*4096 + l)
  int l0 = pos0 & (LSEQ - 1);
  int bq = pos0 >> 12;
  if (l0 >= seq_q[bq] + 2) return;             // h0 needed only for l <= slen+1
  int c0 = lane * 8;

  float w[24], bb[8], gg[8], ee[8];
  for (int v = 0; v < 6; v++)
    *reinterpret_cast<float4*>(w + v * 4) = *reinterpret_cast<const float4*>(w0 + c0 * 3 + v * 4);
  for (int v = 0; v < 2; v++) {
    *reinterpret_cast<float4*>(bb + v * 4) = *reinterpret_cast<const float4*>(b0 + c0 + v * 4);
    *reinterpret_cast<float4*>(gg + v * 4) = *reinterpret_cast<const float4*>(g0 + c0 + v * 4);
    *reinterpret_cast<float4*>(ee + v * 4) = *reinterpret_cast<const float4*>(be0 + c0 + v * 4);
  }
  for (int c = 0; c < 8; c++) gg[c] *= INVS;

  const float* xb = x + (size_t)(pos0 - l0);   // batch base
  unsigned short* hrow = h0 + ((size_t)bq * HSTR + 1 + l0) * HCH + c0;
  for (int pp = 0; pp < 8; pp++) {
    int l = l0 + pp;
    float xm1 = (l > 0) ? xb[l - 1] : 0.f;
    float xc = xb[l];
    float xp1 = (l < LSEQ - 1) ? xb[l + 1] : 0.f;
    unsigned int o[4];
    for (int pq = 0; pq < 4; pq++) {
      unsigned int lo = 0, hi = 0;
      for (int s = 0; s < 2; s++) {
        int c = pq * 2 + s;
        float y = w[c * 3] * xm1 + w[c * 3 + 1] * xc + w[c * 3 + 2] * xp1 + bb[c];
        y = fmaxf(y, 0.f);
        unsigned int u = f2bf(gg[c] * y + ee[c]);
        if (s == 0) lo = u; else hi = u;
      }
      o[pq] = lo | (hi << 16);
    }
    uint4 v4; v4.x = o[0]; v4.y = o[1]; v4.z = o[2]; v4.w = o[3];
    *reinterpret_cast<uint4*>(hrow + (size_t)pp * HCH) = v4;
  }
}

// ---- r3-proven 256x256 GEMM machinery: 3-deep B pipeline, 1 barrier/step -
// K-step t: k = t%3, ci0 = (t/3)*64.  Row stride = HCH shorts, so OFFK's
// (t%3)*HCH term is exactly "+k rows" for both conv (p+k) and chunk (3s+k).
// LDS 160 KiB: A 2 x 32 KB dbuf + B 3 x 32 KB tbuf.
// WAITV(4) before the barrier forces the 8 oldest loads (= B(t) from t-2,
// A(t) from t-1) complete in EVERY wave -> race-free.
#define OFFK(T) (((T) % 3) * HCH + ((T) / 3) * 64)

#define STAGE_A(Mh, AB, TN)                                                 \
  { char* d_ = ldsc + (AB) * 32768 + (Mh) * 16384 + w * 1024;               \
    gl_lds16(aSrc[Mh][0] + OFFK(TN), d_);                                   \
    gl_lds16(aSrc[Mh][1] + OFFK(TN), d_ + 8192); }

#define STAGE_B(Nh, BB, TN)                                                 \
  { char* d_ = ldsc + 65536 + (BB) * 32768 + (Nh) * 16384 + w * 1024;       \
    gl_lds16(bSrc[Nh][0] + OFFK(TN), d_);                                   \
    gl_lds16(bSrc[Nh][1] + OFFK(TN), d_ + 8192); }

#define LOAD_AF(Mh, AB)                                                     \
  _Pragma("unroll") for (int i_ = 0; i_ < 4; ++i_)                          \
  _Pragma("unroll") for (int s_ = 0; s_ < 2; ++s_)                          \
    af[i_][s_] = *reinterpret_cast<const bf16x8*>(                          \
        ldsb + (AB) * 16384 + (Mh) * 8192 + (wm + i_ * 16 + mr) * 64 +      \
        (((s_ * 4 + quad) ^ (mr & 7)) << 3));

#define LOAD_BF(Nh, BB)                                                     \
  _Pragma("unroll") for (int j_ = 0; j_ < 2; ++j_)                          \
  _Pragma("unroll") for (int s_ = 0; s_ < 2; ++s_)                          \
    bfv[Nh][j_][s_] = *reinterpret_cast<const bf16x8*>(                     \
        ldsb + 32768 + (BB) * 16384 + (Nh) * 8192 + (wn + j_ * 16 + mr) * 64 + \
        (((s_ * 4 + quad) ^ (mr & 7)) << 3));

#define MFMA_Q(MB, Nh)                                                      \
  __builtin_amdgcn_s_setprio(1);                                            \
  _Pragma("unroll") for (int i_ = 0; i_ < 4; ++i_)                          \
  _Pragma("unroll") for (int j_ = 0; j_ < 2; ++j_)                          \
  _Pragma("unroll") for (int s_ = 0; s_ < 2; ++s_)                          \
    acc[(MB) + i_][(Nh)*2 + j_] = __builtin_amdgcn_mfma_f32_16x16x32_bf16(  \
        af[i_][s_], bfv[Nh][j_][s_], acc[(MB) + i_][(Nh)*2 + j_], 0, 0, 0); \
  __builtin_amdgcn_s_setprio(0);

#define BARRIER { asm volatile("" ::: "memory");                            \
                  __builtin_amdgcn_s_barrier();                             \
                  asm volatile("" ::: "memory"); }
#define WAITV(n) asm volatile("s_waitcnt vmcnt(" #n ")" ::: "memory");

#define STEP(T)                                                             \
  {                                                                         \
    if ((T) == NT - 1) { WAITV(0); } else { WAITV(4); }                     \
    BARRIER;                                                                \
    if ((T) + 1 < NT) { STAGE_A(0, ((T)+1)&1, (T)+1);                       \
                        STAGE_A(1, ((T)+1)&1, (T)+1); }                     \
    if ((T) + 2 < NT) { STAGE_B(0, ((T)+2)%3, (T)+2);                       \
                        STAGE_B(1, ((T)+2)%3, (T)+2); }                     \
    bf16x8 af[4][2], bfv[2][2][2];                                          \
    LOAD_AF(0, (T)&1);                                                      \
    LOAD_BF(0, (T)%3); LOAD_BF(1, (T)%3);                                   \
    MFMA_Q(0, 0); MFMA_Q(0, 1);                                             \
    LOAD_AF(1, (T)&1);                                                      \
    MFMA_Q(4, 1); MFMA_Q(4, 0);                                             \
  }

__global__ __launch_bounds__(512, 2) void conv_gemm8(
    const unsigned short* __restrict__ hin,   // (nb,HSTR,C) bf16, padded
    const unsigned short* __restrict__ wT,    // (512, 1536) bf16 A-layout
    const float* __restrict__ bconv, const float* __restrict__ g,
    const float* __restrict__ be,
    unsigned short* __restrict__ hout,        // (nb,HSTR,C) bf16, padded
    const int* __restrict__ seq_q, int margin) {
  __shared__ unsigned short ldsb[81920];      // 160 KiB: A 64 KB + B 96 KB

  int f = blockIdx.x;
  int cpx = gridDim.x >> 3;
  int s = (f & 7) * cpx + (f >> 3);
  int cm = (s & 1) << 8;
  int y = s >> 1;
  int b = y >> 4;
  int l0 = (y & 15) << 8;
  int limit = seq_q[b] + margin;
  if (l0 >= limit) return;

  const size_t hb = (size_t)b * HSTR * HCH + HCH;
  int tid = threadIdx.x;
  int w = tid >> 6, lane = tid & 63;
  int quad = lane >> 4, mr = lane & 15;
  int wm = (w >> 2) << 6;
  int wn = (w & 3) << 5;
  int srow = tid >> 3;
  int sslot8 = (((tid & 7) ^ (srow & 7)) << 3);

  const unsigned short* aSrc[2][2];
#pragma unroll
  for (int Mh = 0; Mh < 2; ++Mh)
#pragma unroll
    for (int g2 = 0; g2 < 2; ++g2)
      aSrc[Mh][g2] = wT + (size_t)(cm + Mh * 128 + g2 * 64 + srow) * KDIM + sslot8;
  const unsigned short* bSrc[2][2];
#pragma unroll
  for (int Nh = 0; Nh < 2; ++Nh)
#pragma unroll
    for (int g2 = 0; g2 < 2; ++g2)
      bSrc[Nh][g2] = hin + hb +
          (size_t)(l0 - 1 + Nh * 128 + g2 * 64 + srow) * HCH + sslot8;

  f32x4 acc[8][4] = {};
  char* ldsc = (char*)ldsb;

  STAGE_A(0, 0, 0); STAGE_A(1, 0, 0);
  STAGE_B(0, 0, 0); STAGE_B(1, 0, 0);
  STAGE_B(0, 1, 1); STAGE_B(1, 1, 1);

  STEP(0)  STEP(1)  STEP(2)  STEP(3)  STEP(4)  STEP(5)
  STEP(6)  STEP(7)  STEP(8)  STEP(9)  STEP(10) STEP(11)
  STEP(12) STEP(13) STEP(14) STEP(15) STEP(16) STEP(17)
  STEP(18) STEP(19) STEP(20) STEP(21) STEP(22) STEP(23)

#pragma unroll
  for (int ai = 0; ai < 8; ++ai) {
    int Mh = ai >> 2, i = ai & 3;
    int c = cm + Mh * 128 + wm + i * 16 + quad * 4;
    f32x4 bc = *reinterpret_cast<const f32x4*>(bconv + c);
    f32x4 gg = *reinterpret_cast<const f32x4*>(g + c);
    f32x4 bb = *reinterpret_cast<const f32x4*>(be + c);
#pragma unroll
    for (int aj = 0; aj < 4; ++aj) {
      int Nh = aj >> 1, j = aj & 1;
      int n = l0 + Nh * 128 + wn + j * 16 + (lane & 15);
      if (n >= limit) continue;
      unsigned long long pack = 0;
#pragma unroll
      for (int r = 0; r < 4; ++r) {
        float yv = acc[ai][aj][r] + bc[r];
        yv = fmaxf(yv, 0.f);
        unsigned long long u = f2bf(gg[r] * INVS * yv + bb[r]);
        pack |= u << (16 * r);
      }
      *reinterpret_cast<unsigned long long*>(hout + hb + (size_t)n * HCH + c) = pack;
    }
  }
}

// ---- chunk einsum on the SAME r3 pipeline + fused head -------------------
// B row for slot s, tap kt = h[3s + kt]; base pointer at row 3*slot, OFFK's
// (t%3)*HCH adds kt rows.  Slots > 1365 would read past the padded buffer
// -> clamp those staging pointers to the zeropage (dead slots are
// column-independent in MFMA and discarded by the epilogue guard).
__global__ __launch_bounds__(512, 2) void chunk_gemm8(
    const unsigned short* __restrict__ h2,    // (nb,HSTR,C) bf16, padded
    const unsigned short* __restrict__ wT,    // (512,1536) bf16 A-layout
    const float* __restrict__ pb, const float* __restrict__ fw,
    const int* __restrict__ seq_q,
    const int* __restrict__ cum_q,
    float* __restrict__ partial,
    const unsigned short* __restrict__ zp) {
  __shared__ unsigned short ldsb[81920];      // 160 KiB

  int f = blockIdx.x;
  int cpx = gridDim.x >> 3;                   // gridDim.x % 8 == 0 (192)
  int s = (f & 7) * cpx + (f >> 3);
  int cm = (s & 1) << 8;                      // channel tile 0/256
  int y = s >> 1;
  int b = y / 6;                              // batch-local
  int s_base = (y % 6) << 8;                  // 256-slot tile
  int slen = seq_q[b];
  if (3 * s_base + KW > slen) return;         // whole tile dead

  const size_t hb = (size_t)b * HSTR * HCH + HCH;
  int tid = threadIdx.x;
  int w = tid >> 6, lane = tid & 63;
  int quad = lane >> 4, mr = lane & 15;
  int wm = (w >> 2) << 6;
  int wn = (w & 3) << 5;
  int srow = tid >> 3;
  int sslot8 = (((tid & 7) ^ (srow & 7)) << 3);

  const unsigned short* aSrc[2][2];
#pragma unroll
  for (int Mh = 0; Mh < 2; ++Mh)
#pragma unroll
    for (int g2 = 0; g2 < 2; ++g2)
      aSrc[Mh][g2] = wT + (size_t)(cm + Mh * 128 + g2 * 64 + srow) * KDIM + sslot8;
  const unsigned short* bSrc[2][2];
#pragma unroll
  for (int Nh = 0; Nh < 2; ++Nh)
#pragma unroll
    for (int g2 = 0; g2 < 2; ++g2) {
      int slot = s_base + Nh * 128 + g2 * 64 + srow;
      bSrc[Nh][g2] = (slot <= 1365)
          ? h2 + hb + (size_t)(3 * slot) * HCH + sslot8
          : zp + sslot8;
    }

  f32x4 acc[8][4] = {};
  char* ldsc = (char*)ldsb;

  STAGE_A(0, 0, 0); STAGE_A(1, 0, 0);
  STAGE_B(0, 0, 0); STAGE_B(1, 0, 0);
  STAGE_B(0, 1, 1); STAGE_B(1, 1, 1);

  STEP(0)  STEP(1)  STEP(2)  STEP(3)  STEP(4)  STEP(5)
  STEP(6)  STEP(7)  STEP(8)  STEP(9)  STEP(10) STEP(11)
  STEP(12) STEP(13) STEP(14) STEP(15) STEP(16) STEP(17)
  STEP(18) STEP(19) STEP(20) STEP(21) STEP(22) STEP(23)

  // fused head: per slot, sum relu(acc+pb)*fw over this wave's 128 channels,
  // quad-reduce (quads hold disjoint channel groups), one atomic per slot.
  int nn = lane & 15;
#pragma unroll
  for (int aj = 0; aj < 4; ++aj) {
    int Nh = aj >> 1, jj = aj & 1;
    int sc = s_base + Nh * 128 + wn + jj * 16 + nn;
    float sacc = 0.f;
#pragma unroll
    for (int ai = 0; ai < 8; ++ai) {
      int Mh = ai >> 2, i = ai & 3;
      int c = cm + Mh * 128 + wm + i * 16 + quad * 4;
      f32x4 pbv = *reinterpret_cast<const f32x4*>(pb + c);
      f32x4 fwv = *reinterpret_cast<const f32x4*>(fw + c);
#pragma unroll
      for (int r = 0; r < 4; ++r) {
        float z = acc[ai][aj][r] + pbv[r];
        z = fmaxf(z, 0.f);
        sacc += z * fwv[r];
      }
    }
    sacc += __shfl_xor(sacc, 16, 64);
    sacc += __shfl_xor(sacc, 32, 64);
    if (quad == 0 && 3 * sc + KW <= slen)
      atomicAdd(partial + cum_q[b] + sc, sacc);
  }
}

// ---- final: sigmoid(partial + fb) ----------------------------------------
__global__ void finalize(const float* __restrict__ partial, const float* __restrict__ fb,
                         float* __restrict__ out, int n) {
  int i = blockIdx.x * 256 + threadIdx.x;
  if (i < n) {
    float t = partial[i] + fb[0];
    out[i] = 1.f / (1.f + expf(-t));
  }
}

extern "C" void kernel_launch(void* const* d_in, const int* in_sizes, int n_in,
                              void* d_out, int out_size, void* d_ws, size_t ws_size,
                              hipStream_t stream) {
  (void)in_sizes; (void)n_in;
  const float* x   = (const float*)d_in[0];
  const float* w0  = (const float*)d_in[1];
  const float* b0  = (const float*)d_in[2];
  const float* g0  = (const float*)d_in[3];
  const float* be0 = (const float*)d_in[4];
  const float* w1  = (const float*)d_in[5];
  const float* b1  = (const float*)d_in[6];
  const float* g1  = (const float*)d_in[7];
  const float* be1 = (const float*)d_in[8];
  const float* w2  = (const float*)d_in[9];
  const float* b2  = (const float*)d_in[10];
  const float* g2  = (const float*)d_in[11];
  const float* be2 = (const float*)d_in[12];
  const float* pw  = (const float*)d_in[13];
  const float* pb  = (const float*)d_in[14];
  const float* fw  = (const float*)d_in[15];
  const float* fb  = (const float*)d_in[16];
  const int* seq_lens = (const int*)d_in[17];

  char* ws = (char*)d_ws;
  unsigned short* zeropage = (unsigned short*)ws;          // 4096 B, zeroed
  float* partial = (float*)(ws + 4096);                    // out_size floats, zeroed
  size_t off = 4096 + (size_t)out_size * 4;
  off = (off + 255) & ~(size_t)255;
  int* cum = (int*)(ws + off);                             // NB ints
  off += NB * 4;
  off = (off + 255) & ~(size_t)255;
  unsigned short* wt = (unsigned short*)(ws + off);        // 3 x 512 x 1536 bf16
  off += (size_t)3 * HCH * KDIM * 2;
  off = (off + 255) & ~(size_t)255;
  size_t fixed = off;

  const size_t per_batch = (size_t)HSTR * HCH * 2;         // padded, ~4.2 MiB
  int nb_pass = NB;
  while (nb_pass > 1 && fixed + 2 * per_batch * (size_t)nb_pass > ws_size)
    nb_pass >>= 1;
  unsigned short* h0 = (unsigned short*)(ws + fixed);
  unsigned short* h1 = h0 + (size_t)nb_pass * HSTR * HCH;

  int nzero = 1024 + out_size;
  prep_all<<<(3 * HCH * KDIM) / 256, 256, 0, stream>>>(w1, w2, pw, wt, seq_lens, cum,
                                                       (float*)ws, nzero, h0, nb_pass);

  int npass = NB / nb_pass;
  for (int q = 0; q < npass; q++) {
    const float* xq = x + (size_t)q * nb_pass * LSEQ;
    const int* sq = seq_lens + q * nb_pass;
    int nwg = nb_pass * 32;                  // 2 cm-tiles x 16 l-tiles per batch
    layer0<<<nb_pass * (LSEQ / 32), 256, 0, stream>>>(xq, w0, b0, g0, be0, h0, sq);
    conv_gemm8<<<nwg, 512, 0, stream>>>(h0, wt, b1, g1, be1, h1, sq, 1);
    conv_gemm8<<<nwg, 512, 0, stream>>>(h1, wt + (size_t)HCH * KDIM, b2, g2, be2, h0,
                                        sq, 0);
    int nwg2 = nb_pass * 12;                 // 2 cm-tiles x 6 slot-tiles per batch
    chunk_gemm8<<<nwg2, 512, 0, stream>>>(h0, wt + (size_t)2 * HCH * KDIM, pb, fw,
                                          sq, cum + q * nb_pass, partial, zeropage);
  }
  finalize<<<(out_size + 255) / 256, 256, 0, stream>>>(partial, fb, (float*)d_out, out_size);
}